// Round 4
// baseline (76.306 us; speedup 1.0000x reference)
//
#include <hip/hip_runtime.h>

#define D8      8
#define LPATH   2048
#define NBATCH  64
#define NSTEPS  2047         // L-1 increments
#define NCHUNK  32
#define CSTEPS  64           // increments per chunk (last chunk: 63)
#define SIGLEN  4680         // 8 + 64 + 512 + 4096
#define OFF2    8
#define OFF3    72
#define OFF4    584

__device__ __forceinline__ void load8(const float* __restrict__ p, float* v) {
    float4 a = ((const float4*)p)[0];
    float4 b = ((const float4*)p)[1];
    v[0]=a.x; v[1]=a.y; v[2]=a.z; v[3]=a.w;
    v[4]=b.x; v[5]=b.y; v[6]=b.z; v[7]=b.w;
}
__device__ __forceinline__ void store8(float* __restrict__ p, const float* v) {
    ((float4*)p)[0] = make_float4(v[0],v[1],v[2],v[3]);
    ((float4*)p)[1] = make_float4(v[4],v[5],v[6],v[7]);
}

// ============================ Phase 1 ============================
// Block = 128 threads = 2 waves per chunk; wave w owns k in [4w,4w+4).
// Increments z[s][:] precomputed into LDS by a coalesced prologue; the step
// loop never touches global memory.

__device__ __forceinline__ void zload(const float* __restrict__ zl, int s, int i, int j,
                                      float (&Z)[8], float& Zi, float& Zj) {
    const float4* z4 = (const float4*)zl;
    float4 a = z4[2 * s], b = z4[2 * s + 1];
    Z[0]=a.x; Z[1]=a.y; Z[2]=a.z; Z[3]=a.w;
    Z[4]=b.x; Z[5]=b.y; Z[6]=b.z; Z[7]=b.w;
    Zi = zl[s * 8 + i];   // lanes group by i: 8 banks x 8-lane broadcast
    Zj = zl[s * 8 + j];
}

template<int KB>
__device__ __forceinline__ void sig_step(const float (&Z)[8], float Zi, float Zj,
                                         float (&A4)[4][8], float (&A3)[4],
                                         float& A2, float& a1i) {
    const float p  = Zi * Zj;
    const float uq = a1i * Zj;
    const float c4 = fmaf(uq, 1.f/6.f, fmaf(p, 1.f/24.f, A2 * 0.5f));
    const float c3 = fmaf(uq, 0.5f,    fmaf(p, 1.f/6.f,  A2));
#pragma unroll
    for (int kk = 0; kk < 4; ++kk) {
        const float zk = Z[KB + kk];                 // compile-time index
        const float f  = fmaf(c4, zk, A3[kk]);
#pragma unroll
        for (int l = 0; l < 8; ++l) A4[kk][l] = fmaf(f, Z[l], A4[kk][l]);
        A3[kk] = fmaf(c3, zk, A3[kk]);
    }
    A2 = A2 + fmaf(p, 0.5f, uq);
    a1i += Zi;
}

template<int KB>
__device__ __forceinline__ void chunk_body(const float* __restrict__ zl,
                                           const float* __restrict__ pb,
                                           float* __restrict__ o,
                                           int t0, int t1, int n,
                                           int lane, int i, int j) {
    float A4[4][8], A3[4];
    float A2 = 0.f, a1i = 0.f;
#pragma unroll
    for (int kk = 0; kk < 4; ++kk) {
        A3[kk] = 0.f;
#pragma unroll
        for (int l = 0; l < 8; ++l) A4[kk][l] = 0.f;
    }

    float ZA[8], ZB[8];
    float ZAi, ZAj, ZBi, ZBj;
    zload(zl, 0, i, j, ZA, ZAi, ZAj);

    int s = 0;
    for (; s + 1 < n; s += 2) {
        zload(zl, s + 1, i, j, ZB, ZBi, ZBj);
        sig_step<KB>(ZA, ZAi, ZAj, A4, A3, A2, a1i);
        const int s2 = (s + 2 < n) ? (s + 2) : (n - 1);   // clamped junk prefetch
        zload(zl, s2, i, j, ZA, ZAi, ZAj);
        sig_step<KB>(ZB, ZBi, ZBj, A4, A3, A2, a1i);
    }
    if (s < n) sig_step<KB>(ZA, ZAi, ZAj, A4, A3, A2, a1i);  // odd tail (n=63)

    if (KB == 0) {
        if (lane < 8) o[lane] = pb[(size_t)t1 * D8 + lane] - pb[(size_t)t0 * D8 + lane];
        o[OFF2 + lane] = A2;
    }
    *(float4*)(o + OFF3 + lane * 8 + KB) = make_float4(A3[0], A3[1], A3[2], A3[3]);
#pragma unroll
    for (int kk = 0; kk < 4; ++kk)
        store8(o + OFF4 + lane * 64 + (KB + kk) * 8, A4[kk]);
}

__global__ __launch_bounds__(128, 4) void sig_chunk_kernel(const float* __restrict__ path,
                                                           float* __restrict__ sigs) {
    __shared__ float4 zl4[130];                   // 64 steps x 8 floats (+pad)
    float* zl = (float*)zl4;

    const int wg   = blockIdx.x;                  // b*NCHUNK + c
    const int b    = wg >> 5;
    const int c    = wg & (NCHUNK - 1);
    const int tid  = threadIdx.x;
    const int w    = tid >> 6;
    const int lane = tid & 63;
    const int i    = lane >> 3;
    const int j    = lane & 7;
    const int t0   = c * CSTEPS;
    const int t1   = (t0 + CSTEPS < NSTEPS) ? (t0 + CSTEPS) : NSTEPS;
    const int n    = t1 - t0;                     // 64 or 63
    const float* __restrict__ pb = path + (size_t)b * LPATH * D8;

    // prologue: z[s][m] = p[t0+s+1][m] - p[t0+s][m], one float4 per thread
    if (tid * 4 < n * 8) {
        const float* src = pb + (size_t)t0 * D8 + tid * 4;
        float4 a = *(const float4*)(src + 8);
        float4 bq = *(const float4*)(src);
        zl4[tid] = make_float4(a.x - bq.x, a.y - bq.y, a.z - bq.z, a.w - bq.w);
    }
    __syncthreads();

    float* __restrict__ o = sigs + (size_t)wg * SIGLEN;
    if (w == 0) chunk_body<0>(zl, pb, o, t0, t1, n, lane, i, j);
    else        chunk_body<4>(zl, pb, o, t0, t1, n, lane, i, j);
}

// ============================ Phase 2 ============================
// Single launch: fold all 32 chunk-sigs per batch. 1 block (4 waves) per
// batch; wave w owns k rows {2w,2w+1} of A3/A4; A1/A2/a1i replicated.

template<int NPER>
__global__ __launch_bounds__(256) void sig_combine_kernel(const float* __restrict__ in,
                                                          float* __restrict__ out) {
    const int grp  = blockIdx.x;
    const int tid  = threadIdx.x;
    const int w    = tid >> 6;               // wave id: owns k0 = 2w, 2w+1
    const int lane = tid & 63;
    const int i    = lane >> 3;
    const int j    = lane & 7;
    const int k0   = 2 * w;
    const float* __restrict__ base = in + (size_t)grp * NPER * SIGLEN;

    float A4[2][8], a3[2], A1[8], A2, a1i;
    load8(base, A1);
    a1i = base[i];
    A2  = base[OFF2 + lane];
    {
        float2 v = *(const float2*)(base + OFF3 + lane * 8 + k0);
        a3[0] = v.x; a3[1] = v.y;
    }
    load8(base + OFF4 + lane * 64 + k0 * 8,       A4[0]);
    load8(base + OFF4 + lane * 64 + (k0 + 1) * 8, A4[1]);

#pragma unroll 2
    for (int s = 1; s < NPER; ++s) {
        const float* __restrict__ B = base + (size_t)s * SIGLEN;
        // shared loads
        float B1[8];   load8(B, B1);
        const float b1i = B[i];
        const float b1j = B[j];
        const float b2t = B[OFF2 + lane];
        const float2 b1k  = *(const float2*)(B + k0);                    // B1[k]
        const float2 b3k  = *(const float2*)(B + OFF3 + lane * 8 + k0);  // B3[i,j,k]
        const float2 b2jk = *(const float2*)(B + OFF2 + j * 8 + k0);     // B2[j,k]
        // per-k loads
        float b4r[2][8], b2r[2][8], b3r[2][8];
#pragma unroll
        for (int kk = 0; kk < 2; ++kk) {
            load8(B + OFF4 + lane * 64 + (k0 + kk) * 8, b4r[kk]);  // B4[i,j,k,:]
            load8(B + OFF2 + (k0 + kk) * 8,             b2r[kk]);  // B2[k,:]
            load8(B + OFF3 + j * 64 + (k0 + kk) * 8,    b3r[kk]);  // B3[j,k,:]
        }
        // C4[i,j,k,l] = A4 + B4 + A3[k]*B1[l] + A2*B2[k,l] + A1[i]*B3[j,k,l]
#pragma unroll
        for (int kk = 0; kk < 2; ++kk) {
#pragma unroll
            for (int l = 0; l < 8; ++l) {
                float v = A4[kk][l] + b4r[kk][l];
                v = fmaf(a3[kk], B1[l], v);
                v = fmaf(A2,     b2r[kk][l], v);
                A4[kk][l] = fmaf(a1i, b3r[kk][l], v);
            }
        }
        // C3[i,j,k] = A3 + B3[i,j,k] + A2*B1[k] + A1[i]*B2[j,k]   (own k slice)
        a3[0] = fmaf(a1i, b2jk.x, fmaf(A2, b1k.x, a3[0] + b3k.x));
        a3[1] = fmaf(a1i, b2jk.y, fmaf(A2, b1k.y, a3[1] + b3k.y));
        // C2, C1
        A2 = A2 + fmaf(a1i, b1j, b2t);
#pragma unroll
        for (int m = 0; m < 8; ++m) A1[m] += B1[m];
        a1i += b1i;
    }

    float* __restrict__ o = out + (size_t)grp * SIGLEN;
    if (w == 0) {
        if (lane < 8) o[lane] = A1[lane];
        o[OFF2 + lane] = A2;
    }
    *(float2*)(o + OFF3 + lane * 8 + k0) = make_float2(a3[0], a3[1]);
    store8(o + OFF4 + lane * 64 + k0 * 8,       A4[0]);
    store8(o + OFF4 + lane * 64 + (k0 + 1) * 8, A4[1]);
}

extern "C" void kernel_launch(void* const* d_in, const int* in_sizes, int n_in,
                              void* d_out, int out_size, void* d_ws, size_t ws_size,
                              hipStream_t stream) {
    const float* path = (const float*)d_in[0];
    float* out  = (float*)d_out;
    float* sigs = (float*)d_ws;                 // 64*32*4680 f32 = 38.3 MB

    sig_chunk_kernel<<<NBATCH * NCHUNK, 128, 0, stream>>>(path, sigs);
    sig_combine_kernel<NCHUNK><<<NBATCH, 256, 0, stream>>>(sigs, out);
}

// Round 5
// 52.299 us; speedup vs baseline: 1.4590x; 1.4590x over previous
//
#include <hip/hip_runtime.h>

#define D8      8
#define LPATH   2048
#define NBATCH  64
#define NSTEPS  2047         // L-1 increments
#define NCHUNK  32
#define CSTEPS  64           // increments per chunk (last chunk: 63)
#define SIGLEN  4680         // 8 + 64 + 512 + 4096
#define OFF2    8
#define OFF3    72
#define OFF4    584

__device__ __forceinline__ void load8(const float* __restrict__ p, float* v) {
    float4 a = ((const float4*)p)[0];
    float4 b = ((const float4*)p)[1];
    v[0]=a.x; v[1]=a.y; v[2]=a.z; v[3]=a.w;
    v[4]=b.x; v[5]=b.y; v[6]=b.z; v[7]=b.w;
}
__device__ __forceinline__ void store8(float* __restrict__ p, const float* v) {
    ((float4*)p)[0] = make_float4(v[0],v[1],v[2],v[3]);
    ((float4*)p)[1] = make_float4(v[4],v[5],v[6],v[7]);
}

// ============================ Phase 1 ============================
// Block = 128 threads = 2 waves per chunk; wave w owns k in [4w,4w+4).
// Increments z[s][:] precomputed into LDS by a coalesced prologue; the step
// loop never touches global memory.

__device__ __forceinline__ void zload(const float* __restrict__ zl, int s, int i, int j,
                                      float (&Z)[8], float& Zi, float& Zj) {
    const float4* z4 = (const float4*)zl;
    float4 a = z4[2 * s], b = z4[2 * s + 1];
    Z[0]=a.x; Z[1]=a.y; Z[2]=a.z; Z[3]=a.w;
    Z[4]=b.x; Z[5]=b.y; Z[6]=b.z; Z[7]=b.w;
    Zi = zl[s * 8 + i];   // lanes group by i: 8 banks x 8-lane broadcast
    Zj = zl[s * 8 + j];
}

template<int KB>
__device__ __forceinline__ void sig_step(const float (&Z)[8], float Zi, float Zj,
                                         float (&A4)[4][8], float (&A3)[4],
                                         float& A2, float& a1i) {
    const float p  = Zi * Zj;
    const float uq = a1i * Zj;
    const float c4 = fmaf(uq, 1.f/6.f, fmaf(p, 1.f/24.f, A2 * 0.5f));
    const float c3 = fmaf(uq, 0.5f,    fmaf(p, 1.f/6.f,  A2));
#pragma unroll
    for (int kk = 0; kk < 4; ++kk) {
        const float zk = Z[KB + kk];                 // compile-time index
        const float f  = fmaf(c4, zk, A3[kk]);
#pragma unroll
        for (int l = 0; l < 8; ++l) A4[kk][l] = fmaf(f, Z[l], A4[kk][l]);
        A3[kk] = fmaf(c3, zk, A3[kk]);
    }
    A2 = A2 + fmaf(p, 0.5f, uq);
    a1i += Zi;
}

template<int KB>
__device__ __forceinline__ void chunk_body(const float* __restrict__ zl,
                                           const float* __restrict__ pb,
                                           float* __restrict__ o,
                                           int t0, int t1, int n,
                                           int lane, int i, int j) {
    float A4[4][8], A3[4];
    float A2 = 0.f, a1i = 0.f;
#pragma unroll
    for (int kk = 0; kk < 4; ++kk) {
        A3[kk] = 0.f;
#pragma unroll
        for (int l = 0; l < 8; ++l) A4[kk][l] = 0.f;
    }

    float ZA[8], ZB[8];
    float ZAi, ZAj, ZBi, ZBj;
    zload(zl, 0, i, j, ZA, ZAi, ZAj);

    int s = 0;
    for (; s + 1 < n; s += 2) {
        zload(zl, s + 1, i, j, ZB, ZBi, ZBj);
        sig_step<KB>(ZA, ZAi, ZAj, A4, A3, A2, a1i);
        const int s2 = (s + 2 < n) ? (s + 2) : (n - 1);   // clamped junk prefetch
        zload(zl, s2, i, j, ZA, ZAi, ZAj);
        sig_step<KB>(ZB, ZBi, ZBj, A4, A3, A2, a1i);
    }
    if (s < n) sig_step<KB>(ZA, ZAi, ZAj, A4, A3, A2, a1i);  // odd tail (n=63)

    if (KB == 0) {
        if (lane < 8) o[lane] = pb[(size_t)t1 * D8 + lane] - pb[(size_t)t0 * D8 + lane];
        o[OFF2 + lane] = A2;
    }
    *(float4*)(o + OFF3 + lane * 8 + KB) = make_float4(A3[0], A3[1], A3[2], A3[3]);
#pragma unroll
    for (int kk = 0; kk < 4; ++kk)
        store8(o + OFF4 + lane * 64 + (KB + kk) * 8, A4[kk]);
}

__global__ __launch_bounds__(128, 4) void sig_chunk_kernel(const float* __restrict__ path,
                                                           float* __restrict__ sigs) {
    __shared__ float4 zl4[130];                   // 64 steps x 8 floats (+pad)
    float* zl = (float*)zl4;

    const int wg   = blockIdx.x;                  // b*NCHUNK + c
    const int b    = wg >> 5;
    const int c    = wg & (NCHUNK - 1);
    const int tid  = threadIdx.x;
    const int w    = tid >> 6;
    const int lane = tid & 63;
    const int i    = lane >> 3;
    const int j    = lane & 7;
    const int t0   = c * CSTEPS;
    const int t1   = (t0 + CSTEPS < NSTEPS) ? (t0 + CSTEPS) : NSTEPS;
    const int n    = t1 - t0;                     // 64 or 63
    const float* __restrict__ pb = path + (size_t)b * LPATH * D8;

    // prologue: z[s][m] = p[t0+s+1][m] - p[t0+s][m], one float4 per thread
    if (tid * 4 < n * 8) {
        const float* src = pb + (size_t)t0 * D8 + tid * 4;
        float4 a = *(const float4*)(src + 8);
        float4 bq = *(const float4*)(src);
        zl4[tid] = make_float4(a.x - bq.x, a.y - bq.y, a.z - bq.z, a.w - bq.w);
    }
    __syncthreads();

    float* __restrict__ o = sigs + (size_t)wg * SIGLEN;
    if (w == 0) chunk_body<0>(zl, pb, o, t0, t1, n, lane, i, j);
    else        chunk_body<4>(zl, pb, o, t0, t1, n, lane, i, j);
}

// ============================ Phase 2 ============================
// Two-level k-split Chen combine tree: fold-8 (256 blocks) then fold-4
// (64 blocks). 1 block = 4 waves per group; wave w owns k rows {2w,2w+1}
// of A3/A4; A1/A2/a1i replicated. B streamed from global.

template<int NPER>
__global__ __launch_bounds__(256) void sig_combine_kernel(const float* __restrict__ in,
                                                          float* __restrict__ out) {
    const int grp  = blockIdx.x;
    const int tid  = threadIdx.x;
    const int w    = tid >> 6;               // wave id: owns k0 = 2w, 2w+1
    const int lane = tid & 63;
    const int i    = lane >> 3;
    const int j    = lane & 7;
    const int k0   = 2 * w;
    const float* __restrict__ base = in + (size_t)grp * NPER * SIGLEN;

    float A4[2][8], a3[2], A1[8], A2, a1i;
    load8(base, A1);
    a1i = base[i];
    A2  = base[OFF2 + lane];
    {
        float2 v = *(const float2*)(base + OFF3 + lane * 8 + k0);
        a3[0] = v.x; a3[1] = v.y;
    }
    load8(base + OFF4 + lane * 64 + k0 * 8,       A4[0]);
    load8(base + OFF4 + lane * 64 + (k0 + 1) * 8, A4[1]);

#pragma unroll 2
    for (int s = 1; s < NPER; ++s) {
        const float* __restrict__ B = base + (size_t)s * SIGLEN;
        // shared loads
        float B1[8];   load8(B, B1);
        const float b1i = B[i];
        const float b1j = B[j];
        const float b2t = B[OFF2 + lane];
        const float2 b1k  = *(const float2*)(B + k0);                    // B1[k]
        const float2 b3k  = *(const float2*)(B + OFF3 + lane * 8 + k0);  // B3[i,j,k]
        const float2 b2jk = *(const float2*)(B + OFF2 + j * 8 + k0);     // B2[j,k]
        // per-k loads
        float b4r[2][8], b2r[2][8], b3r[2][8];
#pragma unroll
        for (int kk = 0; kk < 2; ++kk) {
            load8(B + OFF4 + lane * 64 + (k0 + kk) * 8, b4r[kk]);  // B4[i,j,k,:]
            load8(B + OFF2 + (k0 + kk) * 8,             b2r[kk]);  // B2[k,:]
            load8(B + OFF3 + j * 64 + (k0 + kk) * 8,    b3r[kk]);  // B3[j,k,:]
        }
        // C4[i,j,k,l] = A4 + B4 + A3[k]*B1[l] + A2*B2[k,l] + A1[i]*B3[j,k,l]
#pragma unroll
        for (int kk = 0; kk < 2; ++kk) {
#pragma unroll
            for (int l = 0; l < 8; ++l) {
                float v = A4[kk][l] + b4r[kk][l];
                v = fmaf(a3[kk], B1[l], v);
                v = fmaf(A2,     b2r[kk][l], v);
                A4[kk][l] = fmaf(a1i, b3r[kk][l], v);
            }
        }
        // C3[i,j,k] = A3 + B3[i,j,k] + A2*B1[k] + A1[i]*B2[j,k]   (own k slice)
        a3[0] = fmaf(a1i, b2jk.x, fmaf(A2, b1k.x, a3[0] + b3k.x));
        a3[1] = fmaf(a1i, b2jk.y, fmaf(A2, b1k.y, a3[1] + b3k.y));
        // C2, C1
        A2 = A2 + fmaf(a1i, b1j, b2t);
#pragma unroll
        for (int m = 0; m < 8; ++m) A1[m] += B1[m];
        a1i += b1i;
    }

    float* __restrict__ o = out + (size_t)grp * SIGLEN;
    if (w == 0) {
        if (lane < 8) o[lane] = A1[lane];
        o[OFF2 + lane] = A2;
    }
    *(float2*)(o + OFF3 + lane * 8 + k0) = make_float2(a3[0], a3[1]);
    store8(o + OFF4 + lane * 64 + k0 * 8,       A4[0]);
    store8(o + OFF4 + lane * 64 + (k0 + 1) * 8, A4[1]);
}

extern "C" void kernel_launch(void* const* d_in, const int* in_sizes, int n_in,
                              void* d_out, int out_size, void* d_ws, size_t ws_size,
                              hipStream_t stream) {
    const float* path = (const float*)d_in[0];
    float* out   = (float*)d_out;
    float* sigs  = (float*)d_ws;                                  // 64*32*4680 f32 = 38.3 MB
    float* gsigs = sigs + (size_t)NBATCH * NCHUNK * SIGLEN;       // 64*4*4680 f32 = 4.8 MB

    sig_chunk_kernel<<<NBATCH * NCHUNK, 128, 0, stream>>>(path, sigs);
    sig_combine_kernel<8><<<NBATCH * 4, 256, 0, stream>>>(sigs, gsigs);
    sig_combine_kernel<4><<<NBATCH, 256, 0, stream>>>(gsigs, out);
}